// Round 4
// baseline (208.567 us; speedup 1.0000x reference)
//
#include <hip/hip_runtime.h>
#include <hip/hip_bf16.h>

// GraphFourierLayer: B=32, N=4096, C_IN=128, C_OUT=128, M=256
#define BB 32
#define NN 4096
#define CI 128
#define CO 128
#define MM 256
#define KS 8           // K-split factor for stage 1 (N=4096 -> 8 chunks of 512)

typedef __hip_bfloat16 bf16;
typedef __attribute__((ext_vector_type(8))) short bf16x8;
typedef __attribute__((ext_vector_type(4))) float f32x4;

__device__ inline void gl_lds16(const void* g, void* l) {
    __builtin_amdgcn_global_load_lds(
        (const __attribute__((address_space(1))) void*)g,
        (__attribute__((address_space(3))) void*)l, 16, 0, 0);
}

// ---------------------------------------------------------------------------
// Prep 1: U fp32 [N][M] -> Un bf16 [N][M] (stage-3 A) and Ut bf16 [M][N]
// ---------------------------------------------------------------------------
__global__ __launch_bounds__(256) void k_cvtU(const float* __restrict__ U,
                                              bf16* __restrict__ Un,
                                              bf16* __restrict__ Ut) {
    const int n0 = blockIdx.x * 64;
    const int m0 = blockIdx.y * 64;
    __shared__ float tile[64][65];
    const int t = threadIdx.x;
    #pragma unroll
    for (int i = 0; i < 16; ++i) {
        int lin = t + i * 256;
        int r = lin >> 6, c = lin & 63;
        float v = U[(n0 + r) * MM + m0 + c];
        tile[r][c] = v;
        Un[(n0 + r) * MM + m0 + c] = __float2bfloat16(v);
    }
    __syncthreads();
    // vectorized: thread -> (m-row, n-octet); lanes 0..7 = consecutive octets
    #pragma unroll
    for (int pass = 0; pass < 2; ++pass) {
        int no = t & 7;                    // n-octet
        int m  = (t >> 3) + pass * 32;     // m-local
        bf16 tmp[8];
        #pragma unroll
        for (int j = 0; j < 8; ++j) tmp[j] = __float2bfloat16(tile[no * 8 + j][m]);
        *(bf16x8*)&Ut[(long)(m0 + m) * NN + n0 + no * 8] = *(bf16x8*)tmp;
    }
}

// ---------------------------------------------------------------------------
// Prep 2: x fp32 [B][N][C] -> xT bf16 [B][C][N]. float4 loads, bf16x8 stores.
// ---------------------------------------------------------------------------
__global__ __launch_bounds__(256) void k_trx(const float* __restrict__ x,
                                             bf16* __restrict__ xT) {
    const int c0 = blockIdx.x * 64;
    const int n0 = blockIdx.y * 64;
    const int b  = blockIdx.z;
    __shared__ float tile[64][65];
    const int t = threadIdx.x;
    // load: thread -> (n-row, c-quad), float4 coalesced
    #pragma unroll
    for (int pass = 0; pass < 4; ++pass) {
        int r  = (t >> 4) + pass * 16;     // n-local
        int c4 = (t & 15) * 4;             // c-local
        float4 v = *(const float4*)&x[((long)b * NN + n0 + r) * CI + c0 + c4];
        tile[r][c4 + 0] = v.x; tile[r][c4 + 1] = v.y;
        tile[r][c4 + 2] = v.z; tile[r][c4 + 3] = v.w;
    }
    __syncthreads();
    // store: thread -> (c-row, n-octet); lanes 0..7 consecutive octets -> 128B runs
    #pragma unroll
    for (int pass = 0; pass < 2; ++pass) {
        int no = t & 7;
        int c  = (t >> 3) + pass * 32;
        bf16 tmp[8];
        #pragma unroll
        for (int j = 0; j < 8; ++j) tmp[j] = __float2bfloat16(tile[no * 8 + j][c]);
        *(bf16x8*)&xT[((long)b * CI + c0 + c) * NN + n0 + no * 8] = *(bf16x8*)tmp;
    }
}

// ---------------------------------------------------------------------------
// Prep 3: W fp32 [C][O][M] -> Wt bf16 [M][C][O]
// ---------------------------------------------------------------------------
__global__ __launch_bounds__(256) void k_wt(const float* __restrict__ W,
                                            bf16* __restrict__ Wt) {
    const int m0 = blockIdx.x * 64;
    const int o0 = blockIdx.y * 64;
    const int c  = blockIdx.z;
    __shared__ float tile[64][65];
    const int t = threadIdx.x;
    #pragma unroll
    for (int pass = 0; pass < 4; ++pass) {
        int r  = (t >> 4) + pass * 16;     // o-local
        int m4 = (t & 15) * 4;             // m-local
        float4 v = *(const float4*)&W[((long)c * CO + o0 + r) * MM + m0 + m4];
        tile[r][m4 + 0] = v.x; tile[r][m4 + 1] = v.y;
        tile[r][m4 + 2] = v.z; tile[r][m4 + 3] = v.w;
    }
    __syncthreads();
    #pragma unroll
    for (int pass = 0; pass < 2; ++pass) {
        int oo = t & 7;                    // o-octet
        int m  = (t >> 3) + pass * 32;     // m-local
        bf16 tmp[8];
        #pragma unroll
        for (int j = 0; j < 8; ++j) tmp[j] = __float2bfloat16(tile[oo * 8 + j][m]);
        *(bf16x8*)&Wt[((long)(m0 + m) * CI + c) * CO + o0 + oo * 8] = *(bf16x8*)tmp;
    }
}

// ---------------------------------------------------------------------------
// Stage 1 (MFMA, K-split): part[ks][b][m][c] = sum_n Ut[m][n]*xT[b][c][n]
// ---------------------------------------------------------------------------
__global__ __launch_bounds__(256) void k_gemm1(const bf16* __restrict__ Ut,
                                               const bf16* __restrict__ xT,
                                               bf16* __restrict__ part) {
    const int ks = blockIdx.x;
    const int m0 = blockIdx.y * 128;
    const int b  = blockIdx.z;
    __shared__ __align__(16) bf16 As[128 * 32];
    __shared__ __align__(16) bf16 Bs[128 * 32];
    const int t    = threadIdx.x;
    const int lane = t & 63;
    const int wave = t >> 6;
    const int wm   = wave >> 1, wn = wave & 1;
    const int fr   = lane & 15;
    const int kg   = (lane >> 4) * 8;
    f32x4 acc[4][4] = {};
    const long xbase = (long)b * CI * NN;
    for (int kt = 0; kt < 512 / 32; ++kt) {
        const int k0 = ks * 512 + kt * 32;
        #pragma unroll
        for (int i = 0; i < 2; ++i) {
            int lin = t + i * 256;
            int r = lin >> 2, kk = (lin & 3) * 8;
            gl_lds16(&Ut[(long)(m0 + r) * NN + k0 + kk], &As[lin * 8]);
            gl_lds16(&xT[xbase + (long)r * NN + k0 + kk], &Bs[lin * 8]);
        }
        __syncthreads();
        bf16x8 a[4], bfr[4];
        #pragma unroll
        for (int i = 0; i < 4; ++i)
            a[i] = *(const bf16x8*)&As[(wm * 64 + i * 16 + fr) * 32 + kg];
        #pragma unroll
        for (int j = 0; j < 4; ++j)
            bfr[j] = *(const bf16x8*)&Bs[(wn * 64 + j * 16 + fr) * 32 + kg];
        #pragma unroll
        for (int i = 0; i < 4; ++i)
            #pragma unroll
            for (int j = 0; j < 4; ++j)
                acc[i][j] = __builtin_amdgcn_mfma_f32_16x16x32_bf16(a[i], bfr[j], acc[i][j], 0, 0, 0);
        __syncthreads();
    }
    const int quad = (lane >> 4) * 4;
    const long pbase = ((long)ks * BB + b) * MM * CI;
    #pragma unroll
    for (int i = 0; i < 4; ++i) {
        #pragma unroll
        for (int j = 0; j < 4; ++j) {
            int mg = m0 + wm * 64 + i * 16 + quad;
            int cg = wn * 64 + j * 16 + fr;
            #pragma unroll
            for (int r = 0; r < 4; ++r)
                part[pbase + (long)(mg + r) * CI + cg] = __float2bfloat16(acc[i][j][r]);
        }
    }
}

// ---------------------------------------------------------------------------
// Stage 2: reduce K-split partials + per-mode channel mix -> osT[b][o][m] bf16
// ---------------------------------------------------------------------------
__global__ __launch_bounds__(256) void k_mix(const bf16* __restrict__ part,
                                             const bf16* __restrict__ Wt,
                                             bf16* __restrict__ osT) {
    const int blk = blockIdx.x;               // 0..511
    const int mi  = blk >> 1;
    const int m   = (mi & 7) * 32 + (mi >> 3); // XCD swizzle on mode
    const int o0  = (blk & 1) * 64;
    __shared__ float Wl[CI][64];
    __shared__ float xl[CI][36];
    const int t = threadIdx.x;
    const long wb = (long)m * CI * CO;
    #pragma unroll
    for (int i = 0; i < 4; ++i) {
        int ch = t + i * 256;
        int c = ch >> 3, og = (ch & 7) * 8;
        bf16x8 v = *(const bf16x8*)&Wt[wb + (long)c * CO + o0 + og];
        #pragma unroll
        for (int j = 0; j < 8; ++j) Wl[c][og + j] = __bfloat162float(((const bf16*)&v)[j]);
    }
    #pragma unroll
    for (int i = 0; i < 2; ++i) {
        int ch = t + i * 256;
        int b = ch >> 4, c8 = (ch & 15) * 8;
        float s[8] = {};
        #pragma unroll
        for (int ks = 0; ks < KS; ++ks) {
            bf16x8 v = *(const bf16x8*)&part[(((long)ks * BB + b) * MM + m) * CI + c8];
            #pragma unroll
            for (int j = 0; j < 8; ++j) s[j] += __bfloat162float(((const bf16*)&v)[j]);
        }
        #pragma unroll
        for (int j = 0; j < 8; ++j) xl[c8 + j][b] = s[j];
    }
    __syncthreads();
    const int op = t & 63;
    const int bq = t >> 6;
    float acc[8] = {};
    for (int c = 0; c < CI; ++c) {
        float w = Wl[c][op];
        #pragma unroll
        for (int j = 0; j < 8; ++j)
            acc[j] += xl[c][bq * 8 + j] * w;
    }
    #pragma unroll
    for (int j = 0; j < 8; ++j)
        osT[((long)(bq * 8 + j) * CO + o0 + op) * MM + m] = __float2bfloat16(acc[j]);
}

// ---------------------------------------------------------------------------
// Stage 3 (MFMA): out[b][n][o] = sum_m Un[n][m] * osT[b][o][m].
// Single-GEMM view: C[n][(b,o)] = Un @ osT^T, (b,o) rows of osT contiguous.
// 128x256 tile (2 batches per block), K=256, grid 32x16 = 512 blocks.
// ---------------------------------------------------------------------------
__global__ __launch_bounds__(256) void k_gemm3(const bf16* __restrict__ Un,
                                               const bf16* __restrict__ osT,
                                               float* __restrict__ out) {
    const int n0   = blockIdx.x * 128;
    const int col0 = blockIdx.y * 256;        // (b,o) flat: b = col>>7, o = col&127
    __shared__ __align__(16) bf16 As[128 * 32];   // [n][k]  8 KB
    __shared__ __align__(16) bf16 Bs[256 * 32];   // [col][k] 16 KB
    const int t    = threadIdx.x;
    const int lane = t & 63;
    const int wave = t >> 6;
    const int wm   = wave >> 1, wn = wave & 1;    // n-half, col-half(128)
    const int fr   = lane & 15;
    const int kg   = (lane >> 4) * 8;
    f32x4 acc[4][8] = {};
    for (int kt = 0; kt < MM / 32; ++kt) {
        const int k0 = kt * 32;
        #pragma unroll
        for (int i = 0; i < 2; ++i) {
            int lin = t + i * 256;                // 0..511
            int r = lin >> 2, kk = (lin & 3) * 8;
            gl_lds16(&Un[(long)(n0 + r) * MM + k0 + kk], &As[lin * 8]);
        }
        #pragma unroll
        for (int i = 0; i < 4; ++i) {
            int lin = t + i * 256;                // 0..1023
            int r = lin >> 2, kk = (lin & 3) * 8;
            gl_lds16(&osT[(long)(col0 + r) * MM + k0 + kk], &Bs[lin * 8]);
        }
        __syncthreads();
        bf16x8 a[4], bfr[8];
        #pragma unroll
        for (int i = 0; i < 4; ++i)
            a[i] = *(const bf16x8*)&As[(wm * 64 + i * 16 + fr) * 32 + kg];
        #pragma unroll
        for (int j = 0; j < 8; ++j)
            bfr[j] = *(const bf16x8*)&Bs[(wn * 128 + j * 16 + fr) * 32 + kg];
        #pragma unroll
        for (int i = 0; i < 4; ++i)
            #pragma unroll
            for (int j = 0; j < 8; ++j)
                acc[i][j] = __builtin_amdgcn_mfma_f32_16x16x32_bf16(a[i], bfr[j], acc[i][j], 0, 0, 0);
        __syncthreads();
    }
    const int quad = (lane >> 4) * 4;
    #pragma unroll
    for (int i = 0; i < 4; ++i) {
        #pragma unroll
        for (int j = 0; j < 8; ++j) {
            int ng  = n0 + wm * 64 + i * 16 + quad;
            int col = col0 + wn * 128 + j * 16 + fr;
            int b = col >> 7, o = col & 127;
            #pragma unroll
            for (int r = 0; r < 4; ++r)
                out[((long)b * NN + ng + r) * CO + o] = acc[i][j][r];
        }
    }
}

extern "C" void kernel_launch(void* const* d_in, const int* in_sizes, int n_in,
                              void* d_out, int out_size, void* d_ws, size_t ws_size,
                              hipStream_t stream) {
    const float* x  = (const float*)d_in[0];   // [32][4096][128]
    const float* U  = (const float*)d_in[1];   // [4096][256]
    const float* Wr = (const float*)d_in[2];   // [128][128][256]
    float* out = (float*)d_out;                // [32][4096][128]

    char* p = (char*)d_ws;
    bf16* xT   = (bf16*)p;  p += (size_t)BB * CI * NN * 2;        // 32 MB
    bf16* part = (bf16*)p;  p += (size_t)KS * BB * MM * CI * 2;   // 16 MB
    bf16* Ut   = (bf16*)p;  p += (size_t)MM * NN * 2;             // 2 MB
    bf16* Un   = (bf16*)p;  p += (size_t)NN * MM * 2;             // 2 MB
    bf16* osT  = (bf16*)p;  p += (size_t)BB * CO * MM * 2;        // 2 MB
    bf16* Wt   = (bf16*)p;  p += (size_t)MM * CI * CO * 2;        // 8 MB

    k_cvtU <<<dim3(NN / 64, MM / 64), 256, 0, stream>>>(U, Un, Ut);
    k_trx  <<<dim3(CI / 64, NN / 64, BB), 256, 0, stream>>>(x, xT);
    k_wt   <<<dim3(MM / 64, CO / 64, CI), 256, 0, stream>>>(Wr, Wt);
    k_gemm1<<<dim3(KS, MM / 128, BB), 256, 0, stream>>>(Ut, xT, part);
    k_mix  <<<dim3(512), 256, 0, stream>>>(part, Wt, osT);
    k_gemm3<<<dim3(NN / 128, 16), 256, 0, stream>>>(Un, osT, out);
}

// Round 5
// 199.792 us; speedup vs baseline: 1.0439x; 1.0439x over previous
//
#include <hip/hip_runtime.h>
#include <hip/hip_bf16.h>

// GraphFourierLayer: B=32, N=4096, C_IN=128, C_OUT=128, M=256
#define BB 32
#define NN 4096
#define CI 128
#define CO 128
#define MM 256
#define KS 8           // K-split factor for stage 1 (N=4096 -> 8 chunks of 512)

typedef __hip_bfloat16 bf16;
typedef __attribute__((ext_vector_type(8))) short bf16x8;
typedef __attribute__((ext_vector_type(4))) float f32x4;

__device__ inline void gl_lds16(const void* g, void* l) {
    __builtin_amdgcn_global_load_lds(
        (const __attribute__((address_space(1))) void*)g,
        (__attribute__((address_space(3))) void*)l, 16, 0, 0);
}

// ---------------------------------------------------------------------------
// Prep 1: U fp32 [N][M] -> Un bf16 [N][M] (stage-3 A) and Ut bf16 [M][N]
// ---------------------------------------------------------------------------
__global__ __launch_bounds__(256) void k_cvtU(const float* __restrict__ U,
                                              bf16* __restrict__ Un,
                                              bf16* __restrict__ Ut) {
    const int n0 = blockIdx.x * 64;
    const int m0 = blockIdx.y * 64;
    __shared__ float tile[64][65];
    const int t = threadIdx.x;
    #pragma unroll
    for (int i = 0; i < 16; ++i) {
        int lin = t + i * 256;
        int r = lin >> 6, c = lin & 63;
        float v = U[(n0 + r) * MM + m0 + c];
        tile[r][c] = v;
        Un[(n0 + r) * MM + m0 + c] = __float2bfloat16(v);
    }
    __syncthreads();
    // vectorized: thread -> (m-row, n-octet); lanes 0..7 = consecutive octets
    #pragma unroll
    for (int pass = 0; pass < 2; ++pass) {
        int no = t & 7;                    // n-octet
        int m  = (t >> 3) + pass * 32;     // m-local
        bf16 tmp[8];
        #pragma unroll
        for (int j = 0; j < 8; ++j) tmp[j] = __float2bfloat16(tile[no * 8 + j][m]);
        *(bf16x8*)&Ut[(long)(m0 + m) * NN + n0 + no * 8] = *(bf16x8*)tmp;
    }
}

// ---------------------------------------------------------------------------
// Prep 2: x fp32 [B][N][C] -> xT bf16 [B][C][N]. float4 loads, bf16x8 stores.
// ---------------------------------------------------------------------------
__global__ __launch_bounds__(256) void k_trx(const float* __restrict__ x,
                                             bf16* __restrict__ xT) {
    const int c0 = blockIdx.x * 64;
    const int n0 = blockIdx.y * 64;
    const int b  = blockIdx.z;
    __shared__ float tile[64][65];
    const int t = threadIdx.x;
    #pragma unroll
    for (int pass = 0; pass < 4; ++pass) {
        int r  = (t >> 4) + pass * 16;     // n-local
        int c4 = (t & 15) * 4;             // c-local
        float4 v = *(const float4*)&x[((long)b * NN + n0 + r) * CI + c0 + c4];
        tile[r][c4 + 0] = v.x; tile[r][c4 + 1] = v.y;
        tile[r][c4 + 2] = v.z; tile[r][c4 + 3] = v.w;
    }
    __syncthreads();
    #pragma unroll
    for (int pass = 0; pass < 2; ++pass) {
        int no = t & 7;
        int c  = (t >> 3) + pass * 32;
        bf16 tmp[8];
        #pragma unroll
        for (int j = 0; j < 8; ++j) tmp[j] = __float2bfloat16(tile[no * 8 + j][c]);
        *(bf16x8*)&xT[((long)b * CI + c0 + c) * NN + n0 + no * 8] = *(bf16x8*)tmp;
    }
}

// ---------------------------------------------------------------------------
// Prep 3: W fp32 [C][O][M] -> Wt bf16 [M][C][O]
// ---------------------------------------------------------------------------
__global__ __launch_bounds__(256) void k_wt(const float* __restrict__ W,
                                            bf16* __restrict__ Wt) {
    const int m0 = blockIdx.x * 64;
    const int o0 = blockIdx.y * 64;
    const int c  = blockIdx.z;
    __shared__ float tile[64][65];
    const int t = threadIdx.x;
    #pragma unroll
    for (int pass = 0; pass < 4; ++pass) {
        int r  = (t >> 4) + pass * 16;     // o-local
        int m4 = (t & 15) * 4;             // m-local
        float4 v = *(const float4*)&W[((long)c * CO + o0 + r) * MM + m0 + m4];
        tile[r][m4 + 0] = v.x; tile[r][m4 + 1] = v.y;
        tile[r][m4 + 2] = v.z; tile[r][m4 + 3] = v.w;
    }
    __syncthreads();
    #pragma unroll
    for (int pass = 0; pass < 2; ++pass) {
        int oo = t & 7;                    // o-octet
        int m  = (t >> 3) + pass * 32;     // m-local
        bf16 tmp[8];
        #pragma unroll
        for (int j = 0; j < 8; ++j) tmp[j] = __float2bfloat16(tile[oo * 8 + j][m]);
        *(bf16x8*)&Wt[((long)(m0 + m) * CI + c) * CO + o0 + oo * 8] = *(bf16x8*)tmp;
    }
}

// ---------------------------------------------------------------------------
// Stage 1 (MFMA, K-split): part[ks][b][m][c] = sum_n Ut[m][n]*xT[b][c][n]
// ---------------------------------------------------------------------------
__global__ __launch_bounds__(256) void k_gemm1(const bf16* __restrict__ Ut,
                                               const bf16* __restrict__ xT,
                                               bf16* __restrict__ part) {
    const int ks = blockIdx.x;
    const int m0 = blockIdx.y * 128;
    const int b  = blockIdx.z;
    __shared__ __align__(16) bf16 As[128 * 32];
    __shared__ __align__(16) bf16 Bs[128 * 32];
    const int t    = threadIdx.x;
    const int lane = t & 63;
    const int wave = t >> 6;
    const int wm   = wave >> 1, wn = wave & 1;
    const int fr   = lane & 15;
    const int kg   = (lane >> 4) * 8;
    f32x4 acc[4][4] = {};
    const long xbase = (long)b * CI * NN;
    for (int kt = 0; kt < 512 / 32; ++kt) {
        const int k0 = ks * 512 + kt * 32;
        #pragma unroll
        for (int i = 0; i < 2; ++i) {
            int lin = t + i * 256;
            int r = lin >> 2, kk = (lin & 3) * 8;
            gl_lds16(&Ut[(long)(m0 + r) * NN + k0 + kk], &As[lin * 8]);
            gl_lds16(&xT[xbase + (long)r * NN + k0 + kk], &Bs[lin * 8]);
        }
        __syncthreads();
        bf16x8 a[4], bfr[4];
        #pragma unroll
        for (int i = 0; i < 4; ++i)
            a[i] = *(const bf16x8*)&As[(wm * 64 + i * 16 + fr) * 32 + kg];
        #pragma unroll
        for (int j = 0; j < 4; ++j)
            bfr[j] = *(const bf16x8*)&Bs[(wn * 64 + j * 16 + fr) * 32 + kg];
        #pragma unroll
        for (int i = 0; i < 4; ++i)
            #pragma unroll
            for (int j = 0; j < 4; ++j)
                acc[i][j] = __builtin_amdgcn_mfma_f32_16x16x32_bf16(a[i], bfr[j], acc[i][j], 0, 0, 0);
        __syncthreads();
    }
    const int quad = (lane >> 4) * 4;
    const long pbase = ((long)ks * BB + b) * MM * CI;
    #pragma unroll
    for (int i = 0; i < 4; ++i) {
        #pragma unroll
        for (int j = 0; j < 4; ++j) {
            int mg = m0 + wm * 64 + i * 16 + quad;
            int cg = wn * 64 + j * 16 + fr;
            #pragma unroll
            for (int r = 0; r < 4; ++r)
                part[pbase + (long)(mg + r) * CI + cg] = __float2bfloat16(acc[i][j][r]);
        }
    }
}

// ---------------------------------------------------------------------------
// Stage 2: reduce K-split partials + per-mode channel mix -> osT[b][o][m] bf16
// ---------------------------------------------------------------------------
__global__ __launch_bounds__(256) void k_mix(const bf16* __restrict__ part,
                                             const bf16* __restrict__ Wt,
                                             bf16* __restrict__ osT) {
    const int blk = blockIdx.x;               // 0..511
    const int mi  = blk >> 1;
    const int m   = (mi & 7) * 32 + (mi >> 3); // XCD swizzle on mode
    const int o0  = (blk & 1) * 64;
    __shared__ float Wl[CI][64];
    __shared__ float xl[CI][36];
    const int t = threadIdx.x;
    const long wb = (long)m * CI * CO;
    #pragma unroll
    for (int i = 0; i < 4; ++i) {
        int ch = t + i * 256;
        int c = ch >> 3, og = (ch & 7) * 8;
        bf16x8 v = *(const bf16x8*)&Wt[wb + (long)c * CO + o0 + og];
        #pragma unroll
        for (int j = 0; j < 8; ++j) Wl[c][og + j] = __bfloat162float(((const bf16*)&v)[j]);
    }
    #pragma unroll
    for (int i = 0; i < 2; ++i) {
        int ch = t + i * 256;
        int b = ch >> 4, c8 = (ch & 15) * 8;
        float s[8] = {};
        #pragma unroll
        for (int ks = 0; ks < KS; ++ks) {
            bf16x8 v = *(const bf16x8*)&part[(((long)ks * BB + b) * MM + m) * CI + c8];
            #pragma unroll
            for (int j = 0; j < 8; ++j) s[j] += __bfloat162float(((const bf16*)&v)[j]);
        }
        #pragma unroll
        for (int j = 0; j < 8; ++j) xl[c8 + j][b] = s[j];
    }
    __syncthreads();
    const int op = t & 63;
    const int bq = t >> 6;
    float acc[8] = {};
    for (int c = 0; c < CI; ++c) {
        float w = Wl[c][op];
        #pragma unroll
        for (int j = 0; j < 8; ++j)
            acc[j] += xl[c][bq * 8 + j] * w;
    }
    #pragma unroll
    for (int j = 0; j < 8; ++j)
        osT[((long)(bq * 8 + j) * CO + o0 + op) * MM + m] = __float2bfloat16(acc[j]);
}

// ---------------------------------------------------------------------------
// Stage 3 (MFMA): out[b][n][o] = sum_m Un[n][m] * osT[b][o][m]. K=256.
// Reverted to 128x128 tile (R3): acc[4][4]=64 VGPR keeps 3 waves/SIMD;
// the 128x256 variant (R4) cost an occupancy step and regressed +11 us.
// ---------------------------------------------------------------------------
__global__ __launch_bounds__(256) void k_gemm3(const bf16* __restrict__ Un,
                                               const bf16* __restrict__ osT,
                                               float* __restrict__ out) {
    const int n0 = blockIdx.x * 128;
    const int b  = blockIdx.y;
    __shared__ __align__(16) bf16 As[128 * 32];
    __shared__ __align__(16) bf16 Bs[128 * 32];
    const int t    = threadIdx.x;
    const int lane = t & 63;
    const int wave = t >> 6;
    const int wm   = wave >> 1, wn = wave & 1;
    const int fr   = lane & 15;
    const int kg   = (lane >> 4) * 8;
    f32x4 acc[4][4] = {};
    const long bbase = (long)b * CO * MM;
    for (int kt = 0; kt < MM / 32; ++kt) {
        const int k0 = kt * 32;
        #pragma unroll
        for (int i = 0; i < 2; ++i) {
            int lin = t + i * 256;
            int r = lin >> 2, kk = (lin & 3) * 8;
            gl_lds16(&Un[(long)(n0 + r) * MM + k0 + kk], &As[lin * 8]);
            gl_lds16(&osT[bbase + (long)r * MM + k0 + kk], &Bs[lin * 8]);
        }
        __syncthreads();
        bf16x8 a[4], bfr[4];
        #pragma unroll
        for (int i = 0; i < 4; ++i)
            a[i] = *(const bf16x8*)&As[(wm * 64 + i * 16 + fr) * 32 + kg];
        #pragma unroll
        for (int j = 0; j < 4; ++j)
            bfr[j] = *(const bf16x8*)&Bs[(wn * 64 + j * 16 + fr) * 32 + kg];
        #pragma unroll
        for (int i = 0; i < 4; ++i)
            #pragma unroll
            for (int j = 0; j < 4; ++j)
                acc[i][j] = __builtin_amdgcn_mfma_f32_16x16x32_bf16(a[i], bfr[j], acc[i][j], 0, 0, 0);
        __syncthreads();
    }
    const int quad = (lane >> 4) * 4;
    #pragma unroll
    for (int i = 0; i < 4; ++i) {
        #pragma unroll
        for (int j = 0; j < 4; ++j) {
            int ng = n0 + wm * 64 + i * 16 + quad;
            int og = wn * 64 + j * 16 + fr;
            #pragma unroll
            for (int r = 0; r < 4; ++r)
                out[((long)b * NN + ng + r) * CO + og] = acc[i][j][r];
        }
    }
}

extern "C" void kernel_launch(void* const* d_in, const int* in_sizes, int n_in,
                              void* d_out, int out_size, void* d_ws, size_t ws_size,
                              hipStream_t stream) {
    const float* x  = (const float*)d_in[0];   // [32][4096][128]
    const float* U  = (const float*)d_in[1];   // [4096][256]
    const float* Wr = (const float*)d_in[2];   // [128][128][256]
    float* out = (float*)d_out;                // [32][4096][128]

    char* p = (char*)d_ws;
    bf16* xT   = (bf16*)p;  p += (size_t)BB * CI * NN * 2;        // 32 MB
    bf16* part = (bf16*)p;  p += (size_t)KS * BB * MM * CI * 2;   // 16 MB
    bf16* Ut   = (bf16*)p;  p += (size_t)MM * NN * 2;             // 2 MB
    bf16* Un   = (bf16*)p;  p += (size_t)NN * MM * 2;             // 2 MB
    bf16* osT  = (bf16*)p;  p += (size_t)BB * CO * MM * 2;        // 2 MB
    bf16* Wt   = (bf16*)p;  p += (size_t)MM * CI * CO * 2;        // 8 MB

    k_cvtU <<<dim3(NN / 64, MM / 64), 256, 0, stream>>>(U, Un, Ut);
    k_trx  <<<dim3(CI / 64, NN / 64, BB), 256, 0, stream>>>(x, xT);
    k_wt   <<<dim3(MM / 64, CO / 64, CI), 256, 0, stream>>>(Wr, Wt);
    k_gemm1<<<dim3(KS, MM / 128, BB), 256, 0, stream>>>(Ut, xT, part);
    k_mix  <<<dim3(512), 256, 0, stream>>>(part, Wt, osT);
    k_gemm3<<<dim3(NN / 128, BB), 256, 0, stream>>>(Un, osT, out);
}